// Round 6
// baseline (38.630 us; speedup 1.0000x reference)
//
#include <hip/hip_runtime.h>

// SmoothnessLoss: mean over [B,4,H,W] of smooth_l1(stencil(in - tgt)) * mask
// B=16, C=1, H=W=1024, fp32 in/out. Output: single fp32 scalar.
//
// Stencils on d = in - tgt (conv linear => grads(in)-grads(tgt) = grads(d)):
//   fx  = d(y,x-1) - 2 d(y,x) + d(y,x+1)        mask: zero at x==W-1
//   fy  = d(y-1,x) - 2 d(y,x) + d(y+1,x)        mask: zero at y==H-1
//   fd1 = d(y-1,x-1) - 2 d(y,x) + d(y+1,x+1)    mask: zero on all borders
//   fd2 = d(y-1,x+1) - 2 d(y,x) + d(y+1,x-1)    mask: zero on all borders
//
// R6: R1/R2/R3/R5 (four different load structures) all hit the same ~33us
// steady state => supply-side equilibrium (~5 TB/s mixed L3/HBM), not
// latency-MLP. Remaining levers are DEMAND and LOCALITY:
//   - RR=16: halo overhead 25% -> 12.5% (164 -> 147 MB demand)
//   - XCD-chunked strip map: sw=(b&7)*128+(b>>3); consecutive strips (which
//     share halo rows) stay on one XCD; per-XCD HBM stream is sequential.
// If dur is unchanged, the supply ceiling is confirmed -> roofline.

#define BB 16
#define HH 1024
#define WW 1024
#define RR 16   // rows per block-strip; load volume = (RR+2)/RR x ideal

__device__ __forceinline__ float sl1(float v) {
  float ad = fabsf(v);
  float t = fminf(ad, 1.0f);
  return fmaf(0.5f * t, t, ad - t);   // ad<1 ? 0.5 ad^2 : ad-0.5
}

__global__ __launch_bounds__(256) void smooth_partial(
    const float* __restrict__ in, const float* __restrict__ tg,
    float* __restrict__ ws) {
  const int tid  = threadIdx.x;
  const int lane = tid & 63;
  const int wave = tid >> 6;
  const int x0   = tid * 4;                 // 256 threads x 4 cols = W

  // XCD-chunked bijective swizzle over 1024 strips (8 XCDs x 128 strips):
  // blocks b, b+8 -> same XCD, adjacent strips => halo rows L2-hit.
  const int b  = blockIdx.x;
  const int sw = (b & 7) * 128 + (b >> 3);
  const int bi = sw >> 6;                   // image index 0..15
  const int r0 = (sw & 63) * RR;            // strip start row
  const size_t imgBase = (size_t)bi * (HH * WW);

  // ---- phase 1: vec loads for rows r0-1 .. r0+RR (wave-uniform guard) ----
  float4 a4[RR + 2], b4[RR + 2];
  #pragma unroll
  for (int k = 0; k < RR + 2; ++k) {
    const int y = r0 - 1 + k;
    if (y >= 0 && y < HH) {
      const size_t base = imgBase + (size_t)y * WW + x0;
      a4[k] = *reinterpret_cast<const float4*>(in + base);
      b4[k] = *reinterpret_cast<const float4*>(tg + base);
    } else {
      a4[k] = make_float4(0.f, 0.f, 0.f, 0.f);
      b4[k] = make_float4(0.f, 0.f, 0.f, 0.f);
    }
  }

  // ---- phase 2: diffs + halos via shuffle; wave boundaries via LDS ----
  float4 Dc[RR + 2];
  float  Dl[RR + 2], Dr[RR + 2];
  __shared__ float shL[4][RR + 2];   // lane63's Dc.w per wave
  __shared__ float shR[4][RR + 2];   // lane0's  Dc.x per wave

  #pragma unroll
  for (int k = 0; k < RR + 2; ++k) {
    Dc[k].x = a4[k].x - b4[k].x;
    Dc[k].y = a4[k].y - b4[k].y;
    Dc[k].z = a4[k].z - b4[k].z;
    Dc[k].w = a4[k].w - b4[k].w;
    Dl[k] = __shfl_up(Dc[k].w, 1, 64);     // lane-1's .w (lane 0 fixed below)
    Dr[k] = __shfl_down(Dc[k].x, 1, 64);   // lane+1's .x (lane 63 fixed below)
    if (lane == 63) shL[wave][k] = Dc[k].w;
    if (lane == 0)  shR[wave][k] = Dc[k].x;
  }
  __syncthreads();
  #pragma unroll
  for (int k = 0; k < RR + 2; ++k) {
    if (lane == 0)  Dl[k] = (wave > 0) ? shL[wave - 1][k] : 0.f;  // x==0 pad
    if (lane == 63) Dr[k] = (wave < 3) ? shR[wave + 1][k] : 0.f;  // x==1023 pad
  }

  // ---- phase 3: stencils + smooth-L1 + masks ----
  float sum = 0.f;
  #pragma unroll
  for (int k = 0; k < RR; ++k) {
    const int y = r0 + k;
    const float my  = (y == HH - 1) ? 0.f : 1.f;
    const float mdy = (y == 0 || y == HH - 1) ? 0.f : 1.f;
    const float P[6] = {Dl[k  ], Dc[k  ].x, Dc[k  ].y, Dc[k  ].z, Dc[k  ].w, Dr[k  ]};
    const float C[6] = {Dl[k+1], Dc[k+1].x, Dc[k+1].y, Dc[k+1].z, Dc[k+1].w, Dr[k+1]};
    const float N[6] = {Dl[k+2], Dc[k+2].x, Dc[k+2].y, Dc[k+2].z, Dc[k+2].w, Dr[k+2]};
    #pragma unroll
    for (int j = 1; j <= 4; ++j) {
      const int x = x0 + j - 1;
      const float c2 = -2.f * C[j];
      const float fx = (C[j-1] + C[j+1]) + c2;
      const float fy = (P[j]   + N[j]  ) + c2;
      const float f1 = (P[j-1] + N[j+1]) + c2;
      const float f2 = (P[j+1] + N[j-1]) + c2;
      const float mx  = (x == WW - 1) ? 0.f : 1.f;
      const float mdx = (x == 0 || x == WW - 1) ? 0.f : 1.f;
      sum += sl1(fx) * mx + sl1(fy) * my + (sl1(f1) + sl1(f2)) * (mdx * mdy);
    }
  }

  // ---- deterministic block reduction ----
  for (int off = 32; off > 0; off >>= 1) sum += __shfl_down(sum, off, 64);
  __shared__ float shred[4];
  if (lane == 0) shred[wave] = sum;
  __syncthreads();
  if (tid == 0) ws[blockIdx.x] = (shred[0] + shred[1]) + (shred[2] + shred[3]);
}

__global__ __launch_bounds__(256) void smooth_final(
    const float* __restrict__ ws, float* __restrict__ out, int n) {
  float s = 0.f;
  for (int i = threadIdx.x; i < n; i += 256) s += ws[i];
  for (int off = 32; off > 0; off >>= 1) s += __shfl_down(s, off, 64);
  __shared__ float sh[4];
  const int wave = threadIdx.x >> 6, lane = threadIdx.x & 63;
  if (lane == 0) sh[wave] = s;
  __syncthreads();
  if (threadIdx.x == 0) {
    const float scale = 1.0f / (float)((long long)BB * 4LL * HH * WW);
    out[0] = ((sh[0] + sh[1]) + (sh[2] + sh[3])) * scale;
  }
}

extern "C" void kernel_launch(void* const* d_in, const int* in_sizes, int n_in,
                              void* d_out, int out_size, void* d_ws, size_t ws_size,
                              hipStream_t stream) {
  const float* in = (const float*)d_in[0];
  const float* tg = (const float*)d_in[1];
  float* out = (float*)d_out;
  float* ws  = (float*)d_ws;   // 1024 floats = 4 KiB, well under ws_size

  const int nblocks = BB * (HH / RR);  // 1024 blocks, 256 threads each
  smooth_partial<<<nblocks, 256, 0, stream>>>(in, tg, ws);
  smooth_final<<<1, 256, 0, stream>>>(ws, out, nblocks);
}